// Round 8
// baseline (1599.898 us; speedup 1.0000x reference)
//
#include <hip/hip_runtime.h>
#include <hip/hip_bf16.h>
#include <math.h>

typedef unsigned short u16;
typedef unsigned int u32;
typedef __bf16 bf16v8 __attribute__((ext_vector_type(8)));
typedef _Float16 f16v8 __attribute__((ext_vector_type(8)));
typedef __attribute__((ext_vector_type(4))) float f32x4;

#define D_MOD 256
#define NHEAD 8
#define DHEAD 32
#define SEQL 97
#define NTOKE 23

__device__ __forceinline__ float bf2f(u16 u){
  union { unsigned int i; float f; } x; x.i = ((unsigned int)u) << 16; return x.f;
}
// native RNE f32->bf16 (v_cvt_pk_bf16_f32 on gfx950)
__device__ __forceinline__ u16 f2bf(float f){
  return __builtin_bit_cast(u16, (__bf16)f);
}
// fast gelu: A&S 7.1.26 erf, |eps|<=1.5e-7
__device__ __forceinline__ float gelu_fast(float v){
  float z = v * 0.70710678118654752f;
  float az = fabsf(z);
  float t = __builtin_amdgcn_rcpf(fmaf(0.3275911f, az, 1.0f));
  float p = t*(0.254829592f + t*(-0.284496736f + t*(1.421413741f + t*(-1.453152027f + t*1.061405429f))));
  float e = __expf(-z*z);
  float y = 1.0f - p*e;
  float erfz = copysignf(y, z);
  return 0.5f * v * (1.0f + erfz);
}
__device__ __forceinline__ void gld16(const void* g, void* l){
  __builtin_amdgcn_global_load_lds((const __attribute__((address_space(1))) void*)g,
                                   (__attribute__((address_space(3))) void*)l, 16, 0, 0);
}

// ---------- weight prep: f32 (K,N) -> bf16 (N,K), LDS tile transpose
__global__ __launch_bounds__(256) void prep_t(const float* __restrict__ src, u16* __restrict__ dst,
                                              int K, int N, long sStride, long dStride){
  __shared__ float t[32][33];
  const int k0 = blockIdx.x * 32, n0 = blockIdx.y * 32;
  const float* s = src + (long)blockIdx.z * sStride;
  u16* d = dst + (long)blockIdx.z * dStride;
  const int tx = threadIdx.x & 31, ty = threadIdx.x >> 5;
  #pragma unroll
  for (int r = ty; r < 32; r += 8)
    t[r][tx] = s[(long)(k0 + r) * N + n0 + tx];
  __syncthreads();
  #pragma unroll
  for (int r = ty; r < 32; r += 8)
    d[(long)(n0 + r) * K + k0 + tx] = f2bf(t[tx][r]);
}

// ---------- counts / scan / scatter
__global__ void count_k(const int* __restrict__ bids, int* __restrict__ counts, int n){
  int i = blockIdx.x * blockDim.x + threadIdx.x;
  if (i < n) atomicAdd(&counts[bids[i]], 1);
}

__global__ void scan_k(const int* __restrict__ counts, int* __restrict__ starts, int M){
  __shared__ int buf[1024];
  int t = threadIdx.x;
  int v = (t < M) ? counts[t] : 0;
  buf[t] = v;
  __syncthreads();
  for (int o = 1; o < 1024; o <<= 1){
    int x = (t >= o) ? buf[t - o] : 0;
    __syncthreads();
    buf[t] += x;
    __syncthreads();
  }
  if (t < M) starts[t] = buf[t] - v;
}

__global__ __launch_bounds__(64) void cls_fill(u16* __restrict__ seqc, const float* __restrict__ cls_mod,
                                               const int* __restrict__ starts){
  int m = blockIdx.x, t = threadIdx.x;
  long row = (long)starts[m] + m;
  const float4 v = *(const float4*)(cls_mod + t * 4);
  u16* d = seqc + row * D_MOD + t * 4;
  d[0] = f2bf(v.x); d[1] = f2bf(v.y); d[2] = f2bf(v.z); d[3] = f2bf(v.w);
}

__global__ __launch_bounds__(64) void scatter_k(const float* __restrict__ feats, const float* __restrict__ coords,
                          const int* __restrict__ bids, u16* __restrict__ seqc, float* __restrict__ scc){
  int i = blockIdx.x, t = threadIdx.x;
  long row = (long)i + bids[i] + 1;
  const float4 v = *(const float4*)(feats + (long)i * D_MOD + t * 4);
  u16* d = seqc + row * D_MOD + t * 4;
  d[0] = f2bf(v.x); d[1] = f2bf(v.y); d[2] = f2bf(v.z); d[3] = f2bf(v.w);
  if (t < 3) scc[row * 3 + t] = coords[(long)i * 3 + t];
}

// ---------- 128x128 bf16 MFMA GEMM (m97 structure)
template<int EPI> // 0 none, 3 +resid
__global__ __launch_bounds__(256) void gemm128(
    const u16* __restrict__ A, const u16* __restrict__ Wt,
    const float* __restrict__ bias, const u16* __restrict__ resid,
    u16* __restrict__ C, int K, int N)
{
  __shared__ char smemraw[33792];
  u16* As = (u16*)smemraw;
  u16* Bs = (u16*)(smemraw + 8192);
  float* stg = (float*)smemraw;

  const int tid = threadIdx.x;
  const int w = tid >> 6, l = tid & 63;
  const int wr = w >> 1, wc = w & 1;

  const long nwg = (long)gridDim.x * gridDim.y;
  const long orig = (long)blockIdx.y * gridDim.x + blockIdx.x;
  const long q = nwg >> 3, r = nwg & 7;
  const long xcd = orig & 7, idx = orig >> 3;
  const long swz = (xcd < r ? xcd * (q + 1) : r * (q + 1) + (xcd - r) * q) + idx;
  const int colb = (int)(swz % gridDim.x);
  const long rowb = swz / gridDim.x;
  const long row0 = rowb * 128;
  const int col0 = colb * 128;

  const int fr = l & 15;
  const int ko = (l >> 4) * 8;
  f32x4 acc[4][4] = {};

  const int s0 = w * 128 + l;
  const int s1 = s0 + 64;
  const long ar0 = row0 + (s0 >> 2), ar1 = row0 + (s1 >> 2);
  const long br0 = col0 + (s0 >> 2), br1 = col0 + (s1 >> 2);
  const int cg0 = (s0 & 3) * 8, cg1 = (s1 & 3) * 8;
  u16* ldsA0 = As + w * 1024;
  u16* ldsA1 = As + w * 1024 + 512;
  u16* ldsB0 = Bs + w * 1024;
  u16* ldsB1 = Bs + w * 1024 + 512;

  for (int kt = 0; kt < K; kt += 32){
    __syncthreads();
    gld16(A  + ar0 * K + kt + cg0, ldsA0);
    gld16(A  + ar1 * K + kt + cg1, ldsA1);
    gld16(Wt + br0 * K + kt + cg0, ldsB0);
    gld16(Wt + br1 * K + kt + cg1, ldsB1);
    __syncthreads();
    bf16v8 af[4], bfv[4];
    #pragma unroll
    for (int mi = 0; mi < 4; mi++)
      af[mi] = __builtin_bit_cast(bf16v8, *(const uint4*)(As + (wr*64 + mi*16 + fr)*32 + ko));
    #pragma unroll
    for (int ni = 0; ni < 4; ni++)
      bfv[ni] = __builtin_bit_cast(bf16v8, *(const uint4*)(Bs + (wc*64 + ni*16 + fr)*32 + ko));
    #pragma unroll
    for (int mi = 0; mi < 4; mi++)
      #pragma unroll
      for (int ni = 0; ni < 4; ni++)
        acc[mi][ni] = __builtin_amdgcn_mfma_f32_16x16x32_bf16(af[mi], bfv[ni], acc[mi][ni], 0, 0, 0);
  }

  const int rq = (l >> 4) * 4;
  #pragma unroll
  for (int h = 0; h < 2; h++){
    __syncthreads();
    if (wr == h){
      #pragma unroll
      for (int ni = 0; ni < 4; ni++){
        const int coll = wc*64 + ni*16 + fr;
        const float bb = bias[col0 + coll];
        #pragma unroll
        for (int mi = 0; mi < 4; mi++){
          #pragma unroll
          for (int j = 0; j < 4; j++){
            stg[(mi*16 + rq + j) * 132 + coll] = acc[mi][ni][j] + bb;
          }
        }
      }
    }
    __syncthreads();
    #pragma unroll
    for (int i = 0; i < 4; i++){
      const int slot = i * 256 + tid;
      const int rowl = slot >> 4;
      const int cs = (slot & 15) * 8;
      const long gbase = (row0 + h*64 + rowl) * (long)N + col0 + cs;
      float4 lo = *(const float4*)(stg + rowl*132 + cs);
      float4 hi = *(const float4*)(stg + rowl*132 + cs + 4);
      float vv[8] = {lo.x, lo.y, lo.z, lo.w, hi.x, hi.y, hi.z, hi.w};
      if (EPI == 3){
        uint4 rv = *(const uint4*)(resid + gbase);
        const u16* rp = (const u16*)&rv;
        #pragma unroll
        for (int e = 0; e < 8; e++) vv[e] += bf2f(rp[e]);
      }
      uint4 ov;
      u16* op = (u16*)&ov;
      #pragma unroll
      for (int e = 0; e < 8; e++) op[e] = f2bf(vv[e]);
      *(uint4*)(C + gbase) = ov;
    }
  }
}

// ---------- fused FFN: C = act(A@W1+b1)@W2 + b2 + A   (per 128-row block)
// Hidden processed in chunks of 128; H chunk lives in swizzled LDS (never HBM).
template<int ACT> // 1 gelu, 2 relu
__global__ __launch_bounds__(256) void ffn_fused(
    const u16* __restrict__ A, const u16* __restrict__ W1t, const float* __restrict__ b1,
    const u16* __restrict__ W2t, const float* __restrict__ b2,
    u16* __restrict__ C, int H)
{
  __shared__ char smem[49152];
  u16* As = (u16*)smem;              // [128][32] staged, 8KB
  u16* Bs = (u16*)(smem + 8192);     // 8KB
  u16* Hs = (u16*)(smem + 16384);    // [128][128] bf16 swizzled, 32KB
  float* stg = (float*)smem;         // epilogue 32x260 f32 (33.3KB)

  const int tid = threadIdx.x, w = tid >> 6, l = tid & 63;
  const int wr = w >> 1, wc = w & 1;
  const long row0 = (long)blockIdx.x * 128;
  const int fr = l & 15, ko = (l >> 4) * 8, rq = (l >> 4) * 4;

  const int s0 = w * 128 + l, s1 = s0 + 64;
  const long ar0 = row0 + (s0 >> 2), ar1 = row0 + (s1 >> 2);
  const int br0 = (s0 >> 2), br1 = (s1 >> 2);
  const int cg0 = (s0 & 3) * 8, cg1 = (s1 & 3) * 8;
  u16* ldsA0 = As + w * 1024;
  u16* ldsA1 = As + w * 1024 + 512;
  u16* ldsB0 = Bs + w * 1024;
  u16* ldsB1 = Bs + w * 1024 + 512;

  f32x4 acc2a[4][4] = {};
  f32x4 acc2b[4][4] = {};
  const int CH = H >> 7;

  for (int c = 0; c < CH; c++){
    // ---- stage 1: Hc(128x128) = act(A(128x256) @ W1t[c*128..+128)^T + b1)
    f32x4 acc1[4][4] = {};
    const u16* W1c = W1t + (long)(c * 128) * 256;
    for (int kt = 0; kt < 256; kt += 32){
      __syncthreads();
      gld16(A   + ar0 * 256 + kt + cg0, ldsA0);
      gld16(A   + ar1 * 256 + kt + cg1, ldsA1);
      gld16(W1c + (long)br0 * 256 + kt + cg0, ldsB0);
      gld16(W1c + (long)br1 * 256 + kt + cg1, ldsB1);
      __syncthreads();
      bf16v8 af[4], bfv[4];
      #pragma unroll
      for (int mi = 0; mi < 4; mi++)
        af[mi] = __builtin_bit_cast(bf16v8, *(const uint4*)(As + (wr*64 + mi*16 + fr)*32 + ko));
      #pragma unroll
      for (int ni = 0; ni < 4; ni++)
        bfv[ni] = __builtin_bit_cast(bf16v8, *(const uint4*)(Bs + (wc*64 + ni*16 + fr)*32 + ko));
      #pragma unroll
      for (int mi = 0; mi < 4; mi++)
        #pragma unroll
        for (int ni = 0; ni < 4; ni++)
          acc1[mi][ni] = __builtin_amdgcn_mfma_f32_16x16x32_bf16(af[mi], bfv[ni], acc1[mi][ni], 0, 0, 0);
    }
    // ---- act + bf16 -> Hs (swizzled)
    #pragma unroll
    for (int ni = 0; ni < 4; ni++){
      const int hcol = wc*64 + ni*16 + fr;
      const float bb = b1[c*128 + hcol];
      #pragma unroll
      for (int mi = 0; mi < 4; mi++){
        #pragma unroll
        for (int j = 0; j < 4; j++){
          float v = acc1[mi][ni][j] + bb;
          if (ACT == 1) v = gelu_fast(v);
          if (ACT == 2) v = fmaxf(v, 0.0f);
          const int hrow = wr*64 + mi*16 + rq + j;
          Hs[hrow*128 + (hcol ^ ((hrow & 7) << 3))] = f2bf(v);
        }
      }
    }
    __syncthreads();
    // ---- stage 2: acc2 += Hc @ W2t[:, c*128..+128)^T  (B frags direct from global)
    #pragma unroll
    for (int ks = 0; ks < 4; ks++){
      bf16v8 pa[4];
      #pragma unroll
      for (int mi = 0; mi < 4; mi++){
        const int arow = wr*64 + mi*16 + fr;
        pa[mi] = __builtin_bit_cast(bf16v8, *(const uint4*)(Hs + arow*128 + ((ks*32 + ko) ^ ((arow & 7) << 3))));
      }
      #pragma unroll
      for (int ni = 0; ni < 4; ni++){
        const long colA = wc*64 + ni*16 + fr;
        bf16v8 ba = __builtin_bit_cast(bf16v8, *(const uint4*)(W2t + colA * H + c*128 + ks*32 + ko));
        bf16v8 bb2 = __builtin_bit_cast(bf16v8, *(const uint4*)(W2t + (colA + 128) * H + c*128 + ks*32 + ko));
        #pragma unroll
        for (int mi = 0; mi < 4; mi++){
          acc2a[mi][ni] = __builtin_amdgcn_mfma_f32_16x16x32_bf16(pa[mi], ba, acc2a[mi][ni], 0, 0, 0);
          acc2b[mi][ni] = __builtin_amdgcn_mfma_f32_16x16x32_bf16(pa[mi], bb2, acc2b[mi][ni], 0, 0, 0);
        }
      }
    }
    __syncthreads();
  }

  // ---- epilogue: 4 quarters of 32 rows x 256 cols, +b2 +resid(A), coalesced stores
  #pragma unroll
  for (int qh = 0; qh < 4; qh++){
    __syncthreads();
    if (wr == (qh >> 1)){
      #pragma unroll
      for (int mm = 0; mm < 2; mm++){
        const int mi = (qh & 1) * 2 + mm;
        #pragma unroll
        for (int ni = 0; ni < 4; ni++){
          const int ca = wc*64 + ni*16 + fr;
          const float ba = b2[ca], bbq = b2[ca + 128];
          #pragma unroll
          for (int j = 0; j < 4; j++){
            const int lrow = mm*16 + rq + j;
            stg[lrow*260 + ca]       = acc2a[mi][ni][j] + ba;
            stg[lrow*260 + ca + 128] = acc2b[mi][ni][j] + bbq;
          }
        }
      }
    }
    __syncthreads();
    #pragma unroll
    for (int i = 0; i < 4; i++){
      const int slot = i * 256 + tid;
      const int rowl = slot >> 5;
      const int cs = (slot & 31) * 8;
      const long gbase = (row0 + qh*32 + rowl) * 256 + cs;
      float4 lo = *(const float4*)(stg + rowl*260 + cs);
      float4 hi = *(const float4*)(stg + rowl*260 + cs + 4);
      float vv[8] = {lo.x, lo.y, lo.z, lo.w, hi.x, hi.y, hi.z, hi.w};
      uint4 rv = *(const uint4*)(A + gbase);
      const u16* rp = (const u16*)&rv;
      #pragma unroll
      for (int e = 0; e < 8; e++) vv[e] += bf2f(rp[e]);
      uint4 ov;
      u16* op = (u16*)&ov;
      #pragma unroll
      for (int e = 0; e < 8; e++) op[e] = f2bf(vv[e]);
      *(uint4*)(C + gbase) = ov;
    }
  }
}

// ---------- MFMA module attention, S-bucketed (NT = #16-key-tiles, static bounds)
template<int NT>
__global__ __launch_bounds__(256) void mod_attn_t(
    const u16* __restrict__ qkv, const float* __restrict__ scc,
    const float* __restrict__ rel, const int* __restrict__ counts,
    const int* __restrict__ starts, u16* __restrict__ out, int M, int Slo, int Shi)
{
  constexpr int KS  = (NT + 1) / 2;
  constexpr int NK  = NT * 16;
  constexpr int STR = (KS * 32 <= 64) ? 64 : 128;
  constexpr int PBYTES = (NK * STR * 2 > NK * 132) ? NK * STR * 2 : NK * 132;
  __shared__ char PbRaw[PBYTES];
  __shared__ u16 Vt[32 * STR];
  __shared__ float pj[NK];
  u16* Pb = (u16*)PbRaw;

  const int m = blockIdx.x, h = blockIdx.y;
  const int S = counts[m] + 1;
  if (S <= Slo || S > Shi) return;
  const long base = (long)starts[m] + m;
  const int tid = threadIdx.x, w = tid >> 6, l = tid & 63;
  const int fr = l & 15, ko = (l >> 4) * 8;

  if (tid < NK){
    float v = 1e30f;
    if (tid < S){
      const float* s3 = scc + (base + tid) * 3;
      v = s3[0]*rel[h*3] + s3[1]*rel[h*3+1] + s3[2]*rel[h*3+2];
    }
    pj[tid] = v;
  }
  for (int idx = tid; idx < NK*32; idx += 256){
    int key = idx >> 5, d = idx & 31;
    float v = bf2f(qkv[(base + key)*768 + 512 + h*32 + d]);
    v = fminf(fmaxf(v, -60000.0f), 60000.0f);
    _Float16 hv = (_Float16)v;
    Vt[d*STR + (key ^ ((d & 7) << 3))] = __builtin_bit_cast(u16, hv);
  }
  for (int idx = tid; idx < 32*16; idx += 256){
    int d = idx >> 4, c = NK + (idx & 15);
    Vt[d*STR + (c ^ ((d & 7) << 3))] = 0;
  }
  for (int idx = tid; idx < NK*16; idx += 256){
    int row = idx >> 4, c = NK + (idx & 15);
    Pb[row*STR + (c ^ ((row & 7) << 3))] = 0;
  }
  __syncthreads();

  f32x4 accs[2][NT];
  bf16v8 kf[NT];
  #pragma unroll
  for (int nt = 0; nt < NT; nt++)
    kf[nt] = __builtin_bit_cast(bf16v8, *(const uint4*)(qkv + (base + nt*16 + fr)*768 + 256 + h*32 + ko));
  #pragma unroll
  for (int rr2 = 0; rr2 < 2; rr2++){
    const int rt = w + rr2*4;
    if (rt > NT - 1) break;
    bf16v8 qf = __builtin_bit_cast(bf16v8, *(const uint4*)(qkv + (base + rt*16 + fr)*768 + h*32 + ko));
    #pragma unroll
    for (int nt = 0; nt < NT; nt++){
      f32x4 z = {0.f, 0.f, 0.f, 0.f};
      accs[rr2][nt] = __builtin_amdgcn_mfma_f32_16x16x32_bf16(qf, kf[nt], z, 0, 0, 0);
    }
  }

  float pjr[NT];
  #pragma unroll
  for (int nt = 0; nt < NT; nt++) pjr[nt] = pj[nt*16 + fr];
  const float SCALE = 0.17677669529663687f;
  #pragma unroll
  for (int rr2 = 0; rr2 < 2; rr2++){
    const int rt = w + rr2*4;
    if (rt > NT - 1) break;
    #pragma unroll
    for (int j = 0; j < 4; j++){
      float x[NT], mx = -1e30f;
      #pragma unroll
      for (int nt = 0; nt < NT; nt++){
        x[nt] = accs[rr2][nt][j] * SCALE - pjr[nt];
        mx = fmaxf(mx, x[nt]);
      }
      #pragma unroll
      for (int o = 1; o < 16; o <<= 1) mx = fmaxf(mx, __shfl_xor(mx, o));
      float sum = 0.f;
      #pragma unroll
      for (int nt = 0; nt < NT; nt++){
        x[nt] = __expf(x[nt] - mx);
        sum += x[nt];
      }
      #pragma unroll
      for (int o = 1; o < 16; o <<= 1) sum += __shfl_xor(sum, o);
      const float inv = 1.0f / sum;
      const int row = rt*16 + (l >> 4)*4 + j;
      #pragma unroll
      for (int nt = 0; nt < NT; nt++){
        _Float16 hp = (_Float16)(x[nt] * inv);
        Pb[row*STR + ((nt*16 + fr) ^ ((row & 7) << 3))] = __builtin_bit_cast(u16, hp);
      }
    }
  }
  __syncthreads();

  f32x4 accO[2][2];
  #pragma unroll
  for (int rr2 = 0; rr2 < 2; rr2++){
    const int rt = w + rr2*4;
    if (rt > NT - 1) break;
    #pragma unroll
    for (int nt = 0; nt < 2; nt++){
      f32x4 z = {0.f, 0.f, 0.f, 0.f};
      accO[rr2][nt] = z;
    }
    #pragma unroll
    for (int ks = 0; ks < KS; ks++){
      const int prow = rt*16 + fr;
      f16v8 pa = __builtin_bit_cast(f16v8, *(const uint4*)(Pb + prow*STR + ((ks*32 + ko) ^ ((prow & 7) << 3))));
      #pragma unroll
      for (int nt = 0; nt < 2; nt++){
        const int vrow = nt*16 + fr;
        f16v8 vb = __builtin_bit_cast(f16v8, *(const uint4*)(Vt + vrow*STR + ((ks*32 + ko) ^ ((vrow & 7) << 3))));
        accO[rr2][nt] = __builtin_amdgcn_mfma_f32_16x16x32_f16(pa, vb, accO[rr2][nt], 0, 0, 0);
      }
    }
  }
  __syncthreads();

  float* O = (float*)PbRaw;
  #pragma unroll
  for (int rr2 = 0; rr2 < 2; rr2++){
    const int rt = w + rr2*4;
    if (rt > NT - 1) break;
    #pragma unroll
    for (int nt = 0; nt < 2; nt++)
      #pragma unroll
      for (int j = 0; j < 4; j++)
        O[(rt*16 + (l>>4)*4 + j)*33 + nt*16 + fr] = accO[rr2][nt][j];
  }
  __syncthreads();
  for (int idx = tid; idx < NK*16; idx += 256){
    const int row = idx >> 4;
    if (row >= S) continue;
    const int c = (idx & 15) * 2;
    const float f0 = O[row*33 + c], f1 = O[row*33 + c + 1];
    u32 pk = (u32)f2bf(f0) | ((u32)f2bf(f1) << 16);
    *(u32*)(out + (base + row)*256 + h*32 + c) = pk;
  }
}

// ---------- event attention (tiny): per (b,h), scalar
__global__ __launch_bounds__(64) void evt_attn(const u16* __restrict__ qkv, u16* __restrict__ out){
  __shared__ float Ks[NTOKE][DHEAD];
  __shared__ float Vs[NTOKE][DHEAD];
  const int b = blockIdx.x, h = blockIdx.y;
  const long tb = (long)b * NTOKE;
  const int t = threadIdx.x;
  for (int idx = t; idx < NTOKE * DHEAD; idx += 64){
    int j = idx >> 5, d = idx & 31;
    const u16* base = qkv + (tb + j) * 768 + h * DHEAD + d;
    Ks[j][d] = bf2f(base[256]);
    Vs[j][d] = bf2f(base[512]);
  }
  __syncthreads();
  if (t < NTOKE){
    float q[DHEAD];
    const u16* qb = qkv + (tb + t) * 768 + h * DHEAD;
    #pragma unroll
    for (int d = 0; d < DHEAD; d++) q[d] = bf2f(qb[d]);
    float mmax = -1e30f, lsum = 0.0f;
    float acc[DHEAD];
    #pragma unroll
    for (int d = 0; d < DHEAD; d++) acc[d] = 0.0f;
    for (int j = 0; j < NTOKE; j++){
      float s = 0.0f;
      #pragma unroll
      for (int d = 0; d < DHEAD; d++) s += q[d] * Ks[j][d];
      s = s * 0.17677669529663687f;
      if (s > mmax){
        float cor = __expf(mmax - s);
        lsum = lsum * cor + 1.0f;
        #pragma unroll
        for (int d = 0; d < DHEAD; d++) acc[d] = acc[d] * cor + Vs[j][d];
        mmax = s;
      } else {
        float w = __expf(s - mmax);
        lsum += w;
        #pragma unroll
        for (int d = 0; d < DHEAD; d++) acc[d] += w * Vs[j][d];
      }
    }
    float inv = 1.0f / lsum;
    u16* ob = out + (tb + t) * D_MOD + h * DHEAD;
    #pragma unroll
    for (int d = 0; d < DHEAD; d++) ob[d] = f2bf(acc[d] * inv);
  }
}

// ---------- LayerNorm in-place, 4 rows per block
__global__ __launch_bounds__(256) void ln_k(u16* __restrict__ x, const float* __restrict__ s,
                                            const float* __restrict__ b, long nrows){
  const long row = (long)blockIdx.x * 4 + (threadIdx.x >> 6);
  if (row >= nrows) return;
  const int t = threadIdx.x & 63;
  u16* xr = x + row * D_MOD;
  uint2 rv = *(const uint2*)(xr + t * 4);
  float v0 = bf2f((u16)(rv.x & 0xffffu));
  float v1 = bf2f((u16)(rv.x >> 16));
  float v2 = bf2f((u16)(rv.y & 0xffffu));
  float v3 = bf2f((u16)(rv.y >> 16));
  float sum = v0 + v1 + v2 + v3;
  float sq  = v0*v0 + v1*v1 + v2*v2 + v3*v3;
  #pragma unroll
  for (int o = 32; o > 0; o >>= 1){
    sum += __shfl_xor(sum, o, 64);
    sq  += __shfl_xor(sq,  o, 64);
  }
  float mu = sum * (1.0f/256.0f);
  float var = sq * (1.0f/256.0f) - mu*mu;
  float rs = rsqrtf(var + 1e-5f);
  int c = t * 4;
  u16 o0 = f2bf((v0-mu)*rs*s[c+0]+b[c+0]);
  u16 o1 = f2bf((v1-mu)*rs*s[c+1]+b[c+1]);
  u16 o2 = f2bf((v2-mu)*rs*s[c+2]+b[c+2]);
  u16 o3 = f2bf((v3-mu)*rs*s[c+3]+b[c+3]);
  uint2 wv;
  wv.x = (unsigned)o0 | ((unsigned)o1 << 16);
  wv.y = (unsigned)o2 | ((unsigned)o3 << 16);
  *(uint2*)(xr + t * 4) = wv;
}

// ---------- glob MLP stage 1
__global__ __launch_bounds__(256) void glob1_k(const float* __restrict__ xg, const float* __restrict__ w1,
                                               const float* __restrict__ b1, u16* __restrict__ h){
  int b = blockIdx.x, d = threadIdx.x;
  float s = b1[d];
  #pragma unroll
  for (int k = 0; k < 16; k++) s += xg[b*16 + k] * w1[k*256 + d];
  h[(long)b*256 + d] = f2bf(gelu_fast(s));
}

// ---------- event sequence fill
__global__ __launch_bounds__(64) void fill_se(u16* __restrict__ se, const float* __restrict__ cls_task,
                                              const u16* __restrict__ globo, const float* __restrict__ pos_emb,
                                              const float* __restrict__ empty_emb){
  int bt = blockIdx.x;
  int b = bt / NTOKE, tk = bt % NTOKE;
  int t = threadIdx.x;
  u16* d = se + (long)bt * D_MOD;
  #pragma unroll
  for (int j = 0; j < 4; j++){
    int c = t*4 + j;
    float v;
    if (tk < 7) v = cls_task[tk*D_MOD + c];
    else if (tk == 7) v = bf2f(globo[(long)b*D_MOD + c]) + pos_emb[c];
    else v = empty_emb[c] + pos_emb[(tk - 7)*D_MOD + c];
    d[c] = f2bf(v);
  }
}

// ---------- scatter module CLS into event sequence (+pos_emb)
__global__ __launch_bounds__(64) void scatter_mod(u16* __restrict__ se, const u16* __restrict__ seqc,
                                                  const int* __restrict__ m2e, const int* __restrict__ mpos,
                                                  const int* __restrict__ starts,
                                                  const float* __restrict__ pos_emb){
  int m = blockIdx.x, t = threadIdx.x;
  int e = m2e[m], p = mpos[m];
  const u16* src = seqc + ((long)starts[m] + m) * D_MOD;
  u16* dst = se + ((long)e * NTOKE + 8 + p) * D_MOD;
  const float* pe = pos_emb + (long)(1 + p) * D_MOD;
  #pragma unroll
  for (int j = 0; j < 4; j++){
    int c = t*4 + j;
    dst[c] = f2bf(bf2f(src[c]) + pe[c]);
  }
}

// ---------- heads
__global__ __launch_bounds__(64) void heads_k(const u16* __restrict__ se, const float* __restrict__ hw,
                                              const float* __restrict__ hb, float* __restrict__ out){
  int b = blockIdx.x, t = threadIdx.x;
  __shared__ float raw[16];
  if (t < 16){
    int tok = (t < 4) ? 0 : (t <= 8) ? (t - 3) : (t <= 11) ? 5 : 6;
    const u16* e = se + ((long)b * NTOKE + tok) * D_MOD;
    float s = hb[t];
    for (int d = 0; d < 256; d++) s += bf2f(e[d]) * hw[d*16 + t];
    raw[t] = s;
  }
  __syncthreads();
  if (t < 16){
    float v = raw[t];
    float r;
    if (t <= 8 || t == 12){
      r = fmaxf(v, 0.0f) + log1pf(__expf(-fabsf(v)));
    } else if (t <= 11){
      float n = sqrtf(raw[9]*raw[9] + raw[10]*raw[10] + raw[11]*raw[11]);
      r = v / fmaxf(n, 1e-12f);
    } else {
      float n = sqrtf(raw[13]*raw[13] + raw[14]*raw[14] + raw[15]*raw[15]);
      r = v / fmaxf(n, 1e-12f);
    }
    out[b*16 + t] = r;
  }
}

extern "C" void kernel_launch(void* const* d_in, const int* in_sizes, int n_in,
                              void* d_out, int out_size, void* d_ws, size_t ws_size,
                              hipStream_t stream){
  const float* feats      = (const float*)d_in[0];
  const float* coords     = (const float*)d_in[1];
  const int*   batch_ids  = (const int*)d_in[2];
  const int*   m2e        = (const int*)d_in[3];
  const int*   mpos       = (const int*)d_in[4];
  const float* x_glob     = (const float*)d_in[5];
  const float* cls_mod    = (const float*)d_in[6];
  const float* empty_emb  = (const float*)d_in[7];
  const float* cls_task   = (const float*)d_in[8];
  const float* pos_emb    = (const float*)d_in[9];
  const float* mod_attn_w = (const float*)d_in[10];
  const float* mod_attn_b = (const float*)d_in[11];
  const float* mod_rel    = (const float*)d_in[12];
  const float* mod_ln_s   = (const float*)d_in[13];
  const float* mod_ln_b   = (const float*)d_in[14];
  const float* mod_ffn_w1 = (const float*)d_in[15];
  const float* mod_ffn_b1 = (const float*)d_in[16];
  const float* mod_ffn_w2 = (const float*)d_in[17];
  const float* mod_ffn_b2 = (const float*)d_in[18];
  const float* glob_w1    = (const float*)d_in[19];
  const float* glob_b1    = (const float*)d_in[20];
  const float* glob_w2    = (const float*)d_in[21];
  const float* glob_b2    = (const float*)d_in[22];
  const float* evt_attn_w = (const float*)d_in[23];
  const float* evt_attn_b = (const float*)d_in[24];
  const float* evt_ln_s   = (const float*)d_in[25];
  const float* evt_ln_b   = (const float*)d_in[26];
  const float* evt_ffn_w1 = (const float*)d_in[27];
  const float* evt_ffn_b1 = (const float*)d_in[28];
  const float* evt_ffn_w2 = (const float*)d_in[29];
  const float* evt_ffn_b2 = (const float*)d_in[30];
  const float* head_w     = (const float*)d_in[31];
  const float* head_b     = (const float*)d_in[32];
  float* out = (float*)d_out;

  const int N = in_sizes[0] / 256;   // 53346
  const int M = in_sizes[3];         // 960
  const int B = in_sizes[5] / 16;    // 64
  const long CROWS   = (long)M + N;                       // 54306 compact rows
  const long CROWS_P = (((CROWS + 127) >> 7) << 7) + 128; // pad + overrun guard
  const long TE  = (long)B * NTOKE;  // 1472
  const long TEP = 1536;

  char* ws = (char*)d_ws;
  u16* modWT   = (u16*)ws;
  u16* evtWT   = modWT + 8L*65536;
  u16* modF1T  = evtWT + 12L*65536;
  u16* modF2T  = modF1T + 2L*262144;
  u16* evtF1T  = modF2T + 2L*262144;
  u16* evtF2T  = evtF1T + 3L*524288;
  u16* globW2T = evtF2T + 3L*524288;
  size_t off = 11468800;
  int* counts = (int*)(ws + off); off += 16*1024;
  int* starts = (int*)(ws + off); off += 16*1024;
  float* scc  = (float*)(ws + off); off += ((size_t)CROWS_P*12 + 255) & ~(size_t)255;
  u16* seqc   = (u16*)(ws + off); off += (size_t)CROWS_P * D_MOD * 2;
  off = (off + 255) & ~(size_t)255;
  const size_t OFF_BIG = off;
  u16* qkv   = (u16*)(ws + OFF_BIG);                           // CROWS_P x 768
  u16* attno = (u16*)(ws + OFF_BIG + (size_t)CROWS_P*768*2);   // CROWS_P x 256
  u16* se    = (u16*)(ws + OFF_BIG);                           // event stage reuses BIG
  u16* qkvE  = (u16*)(ws + OFF_BIG + 1*1024*1024);
  u16* attnoE= (u16*)(ws + OFF_BIG + 4*1024*1024);
  u16* globh = (u16*)(ws + OFF_BIG + 12*1024*1024);
  u16* globo = (u16*)(ws + OFF_BIG + 13*1024*1024);

  prep_t<<<dim3(8, 8, 8),   256, 0, stream>>>(mod_attn_w, modWT,   256, 256,  65536L, 65536L);
  prep_t<<<dim3(8, 8, 12),  256, 0, stream>>>(evt_attn_w, evtWT,   256, 256,  65536L, 65536L);
  prep_t<<<dim3(8, 32, 2),  256, 0, stream>>>(mod_ffn_w1, modF1T,  256, 1024, 262144L, 262144L);
  prep_t<<<dim3(32, 8, 2),  256, 0, stream>>>(mod_ffn_w2, modF2T,  1024, 256, 262144L, 262144L);
  prep_t<<<dim3(8, 64, 3),  256, 0, stream>>>(evt_ffn_w1, evtF1T,  256, 2048, 524288L, 524288L);
  prep_t<<<dim3(64, 8, 3),  256, 0, stream>>>(evt_ffn_w2, evtF2T,  2048, 256, 524288L, 524288L);
  prep_t<<<dim3(8, 8, 1),   256, 0, stream>>>(glob_w2,    globW2T, 256, 256,  65536L, 65536L);

  hipMemsetAsync(counts, 0, (size_t)M*4, stream);
  hipMemsetAsync(scc, 0, (size_t)CROWS_P*12, stream);
  hipMemsetAsync(seqc + CROWS*D_MOD, 0, (size_t)(CROWS_P - CROWS)*D_MOD*2, stream);
  count_k<<<(N + 255)/256, 256, 0, stream>>>(batch_ids, counts, N);
  scan_k<<<1, 1024, 0, stream>>>(counts, starts, M);
  cls_fill<<<M, 64, 0, stream>>>(seqc, cls_mod, starts);
  scatter_k<<<N, 64, 0, stream>>>(feats, coords, batch_ids, seqc, scc);

  const int RB = (int)(CROWS_P / 128);
  for (int l = 0; l < 2; l++){
    gemm128<0><<<dim3(6, RB), 256, 0, stream>>>(seqc, modWT + (long)l*4*65536,
        mod_attn_b + l*1024, nullptr, qkv, 256, 768);
    mod_attn_t<3><<<dim3(M, NHEAD), 256, 0, stream>>>(qkv, scc, mod_rel + l*24, counts, starts, attno, M, 0, 48);
    mod_attn_t<5><<<dim3(M, NHEAD), 256, 0, stream>>>(qkv, scc, mod_rel + l*24, counts, starts, attno, M, 48, 80);
    mod_attn_t<7><<<dim3(M, NHEAD), 256, 0, stream>>>(qkv, scc, mod_rel + l*24, counts, starts, attno, M, 80, 112);
    gemm128<3><<<dim3(2, RB), 256, 0, stream>>>(attno, modWT + ((long)l*4+3)*65536,
        mod_attn_b + l*1024 + 768, seqc, seqc, 256, 256);
    ln_k<<<(int)((CROWS + 3)/4), 256, 0, stream>>>(seqc, mod_ln_s + (l*2)*256, mod_ln_b + (l*2)*256, CROWS);
    ffn_fused<1><<<RB, 256, 0, stream>>>(seqc, modF1T + (long)l*262144, mod_ffn_b1 + l*1024,
        modF2T + (long)l*262144, mod_ffn_b2 + l*256, seqc, 1024);
    ln_k<<<(int)((CROWS + 3)/4), 256, 0, stream>>>(seqc, mod_ln_s + (l*2+1)*256, mod_ln_b + (l*2+1)*256, CROWS);
  }

  hipMemsetAsync(globh, 0, 128*256*2, stream);
  hipMemsetAsync((void*)se, 0, (size_t)TEP*D_MOD*2, stream);
  glob1_k<<<B, 256, 0, stream>>>(x_glob, glob_w1, glob_b1, globh);
  gemm128<0><<<dim3(2, 1), 256, 0, stream>>>(globh, globW2T, glob_b2, nullptr, globo, 256, 256);
  fill_se<<<(int)TE, 64, 0, stream>>>(se, cls_task, globo, pos_emb, empty_emb);
  scatter_mod<<<M, 64, 0, stream>>>(se, seqc, m2e, mpos, starts, pos_emb);

  const int RE = (int)(TEP / 128);
  for (int l = 0; l < 3; l++){
    gemm128<0><<<dim3(6, RE), 256, 0, stream>>>(se, evtWT + (long)l*4*65536,
        evt_attn_b + l*1024, nullptr, qkvE, 256, 768);
    evt_attn<<<dim3(B, NHEAD), 64, 0, stream>>>(qkvE, attnoE);
    gemm128<3><<<dim3(2, RE), 256, 0, stream>>>(attnoE, evtWT + ((long)l*4+3)*65536,
        evt_attn_b + l*1024 + 768, se, se, 256, 256);
    ln_k<<<(int)((TE + 3)/4), 256, 0, stream>>>(se, evt_ln_s + (l*2)*256, evt_ln_b + (l*2)*256, TE);
    ffn_fused<2><<<RE, 256, 0, stream>>>(se, evtF1T + (long)l*524288, evt_ffn_b1 + l*2048,
        evtF2T + (long)l*524288, evt_ffn_b2 + l*256, se, 2048);
    ln_k<<<(int)((TE + 3)/4), 256, 0, stream>>>(se, evt_ln_s + (l*2+1)*256, evt_ln_b + (l*2+1)*256, TE);
  }

  heads_k<<<B, 64, 0, stream>>>(se, head_w, head_b, out);
}

// Round 9
// 1033.513 us; speedup vs baseline: 1.5480x; 1.5480x over previous
//
#include <hip/hip_runtime.h>
#include <hip/hip_bf16.h>
#include <math.h>

typedef unsigned short u16;
typedef unsigned int u32;
typedef __bf16 bf16v8 __attribute__((ext_vector_type(8)));
typedef _Float16 f16v8 __attribute__((ext_vector_type(8)));
typedef __attribute__((ext_vector_type(4))) float f32x4;

#define D_MOD 256
#define NHEAD 8
#define DHEAD 32
#define SEQL 97
#define NTOKE 23

__device__ __forceinline__ float bf2f(u16 u){
  union { unsigned int i; float f; } x; x.i = ((unsigned int)u) << 16; return x.f;
}
// native RNE f32->bf16 (validated in r8: absmax unchanged)
__device__ __forceinline__ u16 f2bf(float f){
  return __builtin_bit_cast(u16, (__bf16)f);
}
// fast gelu: A&S 7.1.26 erf, |eps|<=1.5e-7
__device__ __forceinline__ float gelu_fast(float v){
  float z = v * 0.70710678118654752f;
  float az = fabsf(z);
  float t = __builtin_amdgcn_rcpf(fmaf(0.3275911f, az, 1.0f));
  float p = t*(0.254829592f + t*(-0.284496736f + t*(1.421413741f + t*(-1.453152027f + t*1.061405429f))));
  float e = __expf(-z*z);
  float y = 1.0f - p*e;
  float erfz = copysignf(y, z);
  return 0.5f * v * (1.0f + erfz);
}
__device__ __forceinline__ void gld16(const void* g, void* l){
  __builtin_amdgcn_global_load_lds((const __attribute__((address_space(1))) void*)g,
                                   (__attribute__((address_space(3))) void*)l, 16, 0, 0);
}

// ---------- weight prep: f32 (K,N) -> bf16 (N,K), LDS tile transpose
__global__ __launch_bounds__(256) void prep_t(const float* __restrict__ src, u16* __restrict__ dst,
                                              int K, int N, long sStride, long dStride){
  __shared__ float t[32][33];
  const int k0 = blockIdx.x * 32, n0 = blockIdx.y * 32;
  const float* s = src + (long)blockIdx.z * sStride;
  u16* d = dst + (long)blockIdx.z * dStride;
  const int tx = threadIdx.x & 31, ty = threadIdx.x >> 5;
  #pragma unroll
  for (int r = ty; r < 32; r += 8)
    t[r][tx] = s[(long)(k0 + r) * N + n0 + tx];
  __syncthreads();
  #pragma unroll
  for (int r = ty; r < 32; r += 8)
    d[(long)(n0 + r) * K + k0 + tx] = f2bf(t[tx][r]);
}

// ---------- counts / scan / scatter (compact layout: module m occupies rows
// [starts[m]+m, starts[m]+m+S_m): CLS inline, then hits)
__global__ void count_k(const int* __restrict__ bids, int* __restrict__ counts, int n){
  int i = blockIdx.x * blockDim.x + threadIdx.x;
  if (i < n) atomicAdd(&counts[bids[i]], 1);
}

__global__ void scan_k(const int* __restrict__ counts, int* __restrict__ starts, int M){
  __shared__ int buf[1024];
  int t = threadIdx.x;
  int v = (t < M) ? counts[t] : 0;
  buf[t] = v;
  __syncthreads();
  for (int o = 1; o < 1024; o <<= 1){
    int x = (t >= o) ? buf[t - o] : 0;
    __syncthreads();
    buf[t] += x;
    __syncthreads();
  }
  if (t < M) starts[t] = buf[t] - v;
}

__global__ __launch_bounds__(64) void cls_fill(u16* __restrict__ seqc, const float* __restrict__ cls_mod,
                                               const int* __restrict__ starts){
  int m = blockIdx.x, t = threadIdx.x;
  long row = (long)starts[m] + m;
  const float4 v = *(const float4*)(cls_mod + t * 4);
  u16* d = seqc + row * D_MOD + t * 4;
  d[0] = f2bf(v.x); d[1] = f2bf(v.y); d[2] = f2bf(v.z); d[3] = f2bf(v.w);
}

__global__ __launch_bounds__(64) void scatter_k(const float* __restrict__ feats, const float* __restrict__ coords,
                          const int* __restrict__ bids, u16* __restrict__ seqc, float* __restrict__ scc){
  int i = blockIdx.x, t = threadIdx.x;
  long row = (long)i + bids[i] + 1;
  const float4 v = *(const float4*)(feats + (long)i * D_MOD + t * 4);
  u16* d = seqc + row * D_MOD + t * 4;
  d[0] = f2bf(v.x); d[1] = f2bf(v.y); d[2] = f2bf(v.z); d[3] = f2bf(v.w);
  if (t < 3) scc[row * 3 + t] = coords[(long)i * 3 + t];
}

// ---------- 128x128 bf16 MFMA GEMM (m97 structure)
template<int EPI> // 0 none, 1 gelu, 2 relu, 3 +resid
__global__ __launch_bounds__(256) void gemm128(
    const u16* __restrict__ A, const u16* __restrict__ Wt,
    const float* __restrict__ bias, const u16* __restrict__ resid,
    u16* __restrict__ C, int K, int N)
{
  __shared__ char smemraw[33792];
  u16* As = (u16*)smemraw;
  u16* Bs = (u16*)(smemraw + 8192);
  float* stg = (float*)smemraw;

  const int tid = threadIdx.x;
  const int w = tid >> 6, l = tid & 63;
  const int wr = w >> 1, wc = w & 1;

  const long nwg = (long)gridDim.x * gridDim.y;
  const long orig = (long)blockIdx.y * gridDim.x + blockIdx.x;
  const long q = nwg >> 3, r = nwg & 7;
  const long xcd = orig & 7, idx = orig >> 3;
  const long swz = (xcd < r ? xcd * (q + 1) : r * (q + 1) + (xcd - r) * q) + idx;
  const int colb = (int)(swz % gridDim.x);
  const long rowb = swz / gridDim.x;
  const long row0 = rowb * 128;
  const int col0 = colb * 128;

  const int fr = l & 15;
  const int ko = (l >> 4) * 8;
  f32x4 acc[4][4] = {};

  const int s0 = w * 128 + l;
  const int s1 = s0 + 64;
  const long ar0 = row0 + (s0 >> 2), ar1 = row0 + (s1 >> 2);
  const long br0 = col0 + (s0 >> 2), br1 = col0 + (s1 >> 2);
  const int cg0 = (s0 & 3) * 8, cg1 = (s1 & 3) * 8;
  u16* ldsA0 = As + w * 1024;
  u16* ldsA1 = As + w * 1024 + 512;
  u16* ldsB0 = Bs + w * 1024;
  u16* ldsB1 = Bs + w * 1024 + 512;

  for (int kt = 0; kt < K; kt += 32){
    __syncthreads();
    gld16(A  + ar0 * K + kt + cg0, ldsA0);
    gld16(A  + ar1 * K + kt + cg1, ldsA1);
    gld16(Wt + br0 * K + kt + cg0, ldsB0);
    gld16(Wt + br1 * K + kt + cg1, ldsB1);
    __syncthreads();
    bf16v8 af[4], bfv[4];
    #pragma unroll
    for (int mi = 0; mi < 4; mi++)
      af[mi] = __builtin_bit_cast(bf16v8, *(const uint4*)(As + (wr*64 + mi*16 + fr)*32 + ko));
    #pragma unroll
    for (int ni = 0; ni < 4; ni++)
      bfv[ni] = __builtin_bit_cast(bf16v8, *(const uint4*)(Bs + (wc*64 + ni*16 + fr)*32 + ko));
    #pragma unroll
    for (int mi = 0; mi < 4; mi++)
      #pragma unroll
      for (int ni = 0; ni < 4; ni++)
        acc[mi][ni] = __builtin_amdgcn_mfma_f32_16x16x32_bf16(af[mi], bfv[ni], acc[mi][ni], 0, 0, 0);
  }

  const int rq = (l >> 4) * 4;
  #pragma unroll
  for (int h = 0; h < 2; h++){
    __syncthreads();
    if (wr == h){
      #pragma unroll
      for (int ni = 0; ni < 4; ni++){
        const int coll = wc*64 + ni*16 + fr;
        const float bb = bias[col0 + coll];
        #pragma unroll
        for (int mi = 0; mi < 4; mi++){
          #pragma unroll
          for (int j = 0; j < 4; j++){
            float v = acc[mi][ni][j] + bb;
            if (EPI == 1) v = gelu_fast(v);
            if (EPI == 2) v = fmaxf(v, 0.0f);
            stg[(mi*16 + rq + j) * 132 + coll] = v;
          }
        }
      }
    }
    __syncthreads();
    #pragma unroll
    for (int i = 0; i < 4; i++){
      const int slot = i * 256 + tid;
      const int rowl = slot >> 4;
      const int cs = (slot & 15) * 8;
      const long gbase = (row0 + h*64 + rowl) * (long)N + col0 + cs;
      float4 lo = *(const float4*)(stg + rowl*132 + cs);
      float4 hi = *(const float4*)(stg + rowl*132 + cs + 4);
      float vv[8] = {lo.x, lo.y, lo.z, lo.w, hi.x, hi.y, hi.z, hi.w};
      if (EPI == 3){
        uint4 rv = *(const uint4*)(resid + gbase);
        const u16* rp = (const u16*)&rv;
        #pragma unroll
        for (int e = 0; e < 8; e++) vv[e] += bf2f(rp[e]);
      }
      uint4 ov;
      u16* op = (u16*)&ov;
      #pragma unroll
      for (int e = 0; e < 8; e++) op[e] = f2bf(vv[e]);
      *(uint4*)(C + gbase) = ov;
    }
  }
}

// ---------- MFMA module attention, S-bucketed (NT = #16-key-tiles, static bounds)
template<int NT>
__global__ __launch_bounds__(256) void mod_attn_t(
    const u16* __restrict__ qkv, const float* __restrict__ scc,
    const float* __restrict__ rel, const int* __restrict__ counts,
    const int* __restrict__ starts, u16* __restrict__ out, int M, int Slo, int Shi)
{
  constexpr int KS  = (NT + 1) / 2;
  constexpr int NK  = NT * 16;
  constexpr int STR = (KS * 32 <= 64) ? 64 : 128;
  constexpr int PBYTES = (NK * STR * 2 > NK * 132) ? NK * STR * 2 : NK * 132;
  __shared__ char PbRaw[PBYTES];
  __shared__ u16 Vt[32 * STR];
  __shared__ float pj[NK];
  u16* Pb = (u16*)PbRaw;

  const int m = blockIdx.x, h = blockIdx.y;
  const int S = counts[m] + 1;
  if (S <= Slo || S > Shi) return;
  const long base = (long)starts[m] + m;
  const int tid = threadIdx.x, w = tid >> 6, l = tid & 63;
  const int fr = l & 15, ko = (l >> 4) * 8;

  if (tid < NK){
    float v = 1e30f;
    if (tid < S){
      const float* s3 = scc + (base + tid) * 3;
      v = s3[0]*rel[h*3] + s3[1]*rel[h*3+1] + s3[2]*rel[h*3+2];
    }
    pj[tid] = v;
  }
  for (int idx = tid; idx < NK*32; idx += 256){
    int key = idx >> 5, d = idx & 31;
    float v = bf2f(qkv[(base + key)*768 + 512 + h*32 + d]);
    v = fminf(fmaxf(v, -60000.0f), 60000.0f);
    _Float16 hv = (_Float16)v;
    Vt[d*STR + (key ^ ((d & 7) << 3))] = __builtin_bit_cast(u16, hv);
  }
  for (int idx = tid; idx < 32*16; idx += 256){
    int d = idx >> 4, c = NK + (idx & 15);
    Vt[d*STR + (c ^ ((d & 7) << 3))] = 0;
  }
  for (int idx = tid; idx < NK*16; idx += 256){
    int row = idx >> 4, c = NK + (idx & 15);
    Pb[row*STR + (c ^ ((row & 7) << 3))] = 0;
  }
  __syncthreads();

  f32x4 accs[2][NT];
  bf16v8 kf[NT];
  #pragma unroll
  for (int nt = 0; nt < NT; nt++)
    kf[nt] = __builtin_bit_cast(bf16v8, *(const uint4*)(qkv + (base + nt*16 + fr)*768 + 256 + h*32 + ko));
  #pragma unroll
  for (int rr2 = 0; rr2 < 2; rr2++){
    const int rt = w + rr2*4;
    if (rt > NT - 1) break;
    bf16v8 qf = __builtin_bit_cast(bf16v8, *(const uint4*)(qkv + (base + rt*16 + fr)*768 + h*32 + ko));
    #pragma unroll
    for (int nt = 0; nt < NT; nt++){
      f32x4 z = {0.f, 0.f, 0.f, 0.f};
      accs[rr2][nt] = __builtin_amdgcn_mfma_f32_16x16x32_bf16(qf, kf[nt], z, 0, 0, 0);
    }
  }

  float pjr[NT];
  #pragma unroll
  for (int nt = 0; nt < NT; nt++) pjr[nt] = pj[nt*16 + fr];
  const float SCALE = 0.17677669529663687f;
  #pragma unroll
  for (int rr2 = 0; rr2 < 2; rr2++){
    const int rt = w + rr2*4;
    if (rt > NT - 1) break;
    #pragma unroll
    for (int j = 0; j < 4; j++){
      float x[NT], mx = -1e30f;
      #pragma unroll
      for (int nt = 0; nt < NT; nt++){
        x[nt] = accs[rr2][nt][j] * SCALE - pjr[nt];
        mx = fmaxf(mx, x[nt]);
      }
      #pragma unroll
      for (int o = 1; o < 16; o <<= 1) mx = fmaxf(mx, __shfl_xor(mx, o));
      float sum = 0.f;
      #pragma unroll
      for (int nt = 0; nt < NT; nt++){
        x[nt] = __expf(x[nt] - mx);
        sum += x[nt];
      }
      #pragma unroll
      for (int o = 1; o < 16; o <<= 1) sum += __shfl_xor(sum, o);
      const float inv = 1.0f / sum;
      const int row = rt*16 + (l >> 4)*4 + j;
      #pragma unroll
      for (int nt = 0; nt < NT; nt++){
        _Float16 hp = (_Float16)(x[nt] * inv);
        Pb[row*STR + ((nt*16 + fr) ^ ((row & 7) << 3))] = __builtin_bit_cast(u16, hp);
      }
    }
  }
  __syncthreads();

  f32x4 accO[2][2];
  #pragma unroll
  for (int rr2 = 0; rr2 < 2; rr2++){
    const int rt = w + rr2*4;
    if (rt > NT - 1) break;
    #pragma unroll
    for (int nt = 0; nt < 2; nt++){
      f32x4 z = {0.f, 0.f, 0.f, 0.f};
      accO[rr2][nt] = z;
    }
    #pragma unroll
    for (int ks = 0; ks < KS; ks++){
      const int prow = rt*16 + fr;
      f16v8 pa = __builtin_bit_cast(f16v8, *(const uint4*)(Pb + prow*STR + ((ks*32 + ko) ^ ((prow & 7) << 3))));
      #pragma unroll
      for (int nt = 0; nt < 2; nt++){
        const int vrow = nt*16 + fr;
        f16v8 vb = __builtin_bit_cast(f16v8, *(const uint4*)(Vt + vrow*STR + ((ks*32 + ko) ^ ((vrow & 7) << 3))));
        accO[rr2][nt] = __builtin_amdgcn_mfma_f32_16x16x32_f16(pa, vb, accO[rr2][nt], 0, 0, 0);
      }
    }
  }
  __syncthreads();

  float* O = (float*)PbRaw;
  #pragma unroll
  for (int rr2 = 0; rr2 < 2; rr2++){
    const int rt = w + rr2*4;
    if (rt > NT - 1) break;
    #pragma unroll
    for (int nt = 0; nt < 2; nt++)
      #pragma unroll
      for (int j = 0; j < 4; j++)
        O[(rt*16 + (l>>4)*4 + j)*33 + nt*16 + fr] = accO[rr2][nt][j];
  }
  __syncthreads();
  for (int idx = tid; idx < NK*16; idx += 256){
    const int row = idx >> 4;
    if (row >= S) continue;
    const int c = (idx & 15) * 2;
    const float f0 = O[row*33 + c], f1 = O[row*33 + c + 1];
    u32 pk = (u32)f2bf(f0) | ((u32)f2bf(f1) << 16);
    *(u32*)(out + (base + row)*256 + h*32 + c) = pk;
  }
}

// ---------- event attention (tiny): per (b,h), scalar
__global__ __launch_bounds__(64) void evt_attn(const u16* __restrict__ qkv, u16* __restrict__ out){
  __shared__ float Ks[NTOKE][DHEAD];
  __shared__ float Vs[NTOKE][DHEAD];
  const int b = blockIdx.x, h = blockIdx.y;
  const long tb = (long)b * NTOKE;
  const int t = threadIdx.x;
  for (int idx = t; idx < NTOKE * DHEAD; idx += 64){
    int j = idx >> 5, d = idx & 31;
    const u16* base = qkv + (tb + j) * 768 + h * DHEAD + d;
    Ks[j][d] = bf2f(base[256]);
    Vs[j][d] = bf2f(base[512]);
  }
  __syncthreads();
  if (t < NTOKE){
    float q[DHEAD];
    const u16* qb = qkv + (tb + t) * 768 + h * DHEAD;
    #pragma unroll
    for (int d = 0; d < DHEAD; d++) q[d] = bf2f(qb[d]);
    float mmax = -1e30f, lsum = 0.0f;
    float acc[DHEAD];
    #pragma unroll
    for (int d = 0; d < DHEAD; d++) acc[d] = 0.0f;
    for (int j = 0; j < NTOKE; j++){
      float s = 0.0f;
      #pragma unroll
      for (int d = 0; d < DHEAD; d++) s += q[d] * Ks[j][d];
      s = s * 0.17677669529663687f;
      if (s > mmax){
        float cor = __expf(mmax - s);
        lsum = lsum * cor + 1.0f;
        #pragma unroll
        for (int d = 0; d < DHEAD; d++) acc[d] = acc[d] * cor + Vs[j][d];
        mmax = s;
      } else {
        float w = __expf(s - mmax);
        lsum += w;
        #pragma unroll
        for (int d = 0; d < DHEAD; d++) acc[d] += w * Vs[j][d];
      }
    }
    float inv = 1.0f / lsum;
    u16* ob = out + (tb + t) * D_MOD + h * DHEAD;
    #pragma unroll
    for (int d = 0; d < DHEAD; d++) ob[d] = f2bf(acc[d] * inv);
  }
}

// ---------- LayerNorm in-place, 4 rows per block
__global__ __launch_bounds__(256) void ln_k(u16* __restrict__ x, const float* __restrict__ s,
                                            const float* __restrict__ b, long nrows){
  const long row = (long)blockIdx.x * 4 + (threadIdx.x >> 6);
  if (row >= nrows) return;
  const int t = threadIdx.x & 63;
  u16* xr = x + row * D_MOD;
  uint2 rv = *(const uint2*)(xr + t * 4);
  float v0 = bf2f((u16)(rv.x & 0xffffu));
  float v1 = bf2f((u16)(rv.x >> 16));
  float v2 = bf2f((u16)(rv.y & 0xffffu));
  float v3 = bf2f((u16)(rv.y >> 16));
  float sum = v0 + v1 + v2 + v3;
  float sq  = v0*v0 + v1*v1 + v2*v2 + v3*v3;
  #pragma unroll
  for (int o = 32; o > 0; o >>= 1){
    sum += __shfl_xor(sum, o, 64);
    sq  += __shfl_xor(sq,  o, 64);
  }
  float mu = sum * (1.0f/256.0f);
  float var = sq * (1.0f/256.0f) - mu*mu;
  float rs = rsqrtf(var + 1e-5f);
  int c = t * 4;
  u16 o0 = f2bf((v0-mu)*rs*s[c+0]+b[c+0]);
  u16 o1 = f2bf((v1-mu)*rs*s[c+1]+b[c+1]);
  u16 o2 = f2bf((v2-mu)*rs*s[c+2]+b[c+2]);
  u16 o3 = f2bf((v3-mu)*rs*s[c+3]+b[c+3]);
  uint2 wv;
  wv.x = (unsigned)o0 | ((unsigned)o1 << 16);
  wv.y = (unsigned)o2 | ((unsigned)o3 << 16);
  *(uint2*)(xr + t * 4) = wv;
}

// ---------- glob MLP stage 1
__global__ __launch_bounds__(256) void glob1_k(const float* __restrict__ xg, const float* __restrict__ w1,
                                               const float* __restrict__ b1, u16* __restrict__ h){
  int b = blockIdx.x, d = threadIdx.x;
  float s = b1[d];
  #pragma unroll
  for (int k = 0; k < 16; k++) s += xg[b*16 + k] * w1[k*256 + d];
  h[(long)b*256 + d] = f2bf(gelu_fast(s));
}

// ---------- event sequence fill
__global__ __launch_bounds__(64) void fill_se(u16* __restrict__ se, const float* __restrict__ cls_task,
                                              const u16* __restrict__ globo, const float* __restrict__ pos_emb,
                                              const float* __restrict__ empty_emb){
  int bt = blockIdx.x;
  int b = bt / NTOKE, tk = bt % NTOKE;
  int t = threadIdx.x;
  u16* d = se + (long)bt * D_MOD;
  #pragma unroll
  for (int j = 0; j < 4; j++){
    int c = t*4 + j;
    float v;
    if (tk < 7) v = cls_task[tk*D_MOD + c];
    else if (tk == 7) v = bf2f(globo[(long)b*D_MOD + c]) + pos_emb[c];
    else v = empty_emb[c] + pos_emb[(tk - 7)*D_MOD + c];
    d[c] = f2bf(v);
  }
}

// ---------- scatter module CLS into event sequence (+pos_emb)
__global__ __launch_bounds__(64) void scatter_mod(u16* __restrict__ se, const u16* __restrict__ seqc,
                                                  const int* __restrict__ m2e, const int* __restrict__ mpos,
                                                  const int* __restrict__ starts,
                                                  const float* __restrict__ pos_emb){
  int m = blockIdx.x, t = threadIdx.x;
  int e = m2e[m], p = mpos[m];
  const u16* src = seqc + ((long)starts[m] + m) * D_MOD;
  u16* dst = se + ((long)e * NTOKE + 8 + p) * D_MOD;
  const float* pe = pos_emb + (long)(1 + p) * D_MOD;
  #pragma unroll
  for (int j = 0; j < 4; j++){
    int c = t*4 + j;
    dst[c] = f2bf(bf2f(src[c]) + pe[c]);
  }
}

// ---------- heads
__global__ __launch_bounds__(64) void heads_k(const u16* __restrict__ se, const float* __restrict__ hw,
                                              const float* __restrict__ hb, float* __restrict__ out){
  int b = blockIdx.x, t = threadIdx.x;
  __shared__ float raw[16];
  if (t < 16){
    int tok = (t < 4) ? 0 : (t <= 8) ? (t - 3) : (t <= 11) ? 5 : 6;
    const u16* e = se + ((long)b * NTOKE + tok) * D_MOD;
    float s = hb[t];
    for (int d = 0; d < 256; d++) s += bf2f(e[d]) * hw[d*16 + t];
    raw[t] = s;
  }
  __syncthreads();
  if (t < 16){
    float v = raw[t];
    float r;
    if (t <= 8 || t == 12){
      r = fmaxf(v, 0.0f) + log1pf(__expf(-fabsf(v)));
    } else if (t <= 11){
      float n = sqrtf(raw[9]*raw[9] + raw[10]*raw[10] + raw[11]*raw[11]);
      r = v / fmaxf(n, 1e-12f);
    } else {
      float n = sqrtf(raw[13]*raw[13] + raw[14]*raw[14] + raw[15]*raw[15]);
      r = v / fmaxf(n, 1e-12f);
    }
    out[b*16 + t] = r;
  }
}

extern "C" void kernel_launch(void* const* d_in, const int* in_sizes, int n_in,
                              void* d_out, int out_size, void* d_ws, size_t ws_size,
                              hipStream_t stream){
  const float* feats      = (const float*)d_in[0];
  const float* coords     = (const float*)d_in[1];
  const int*   batch_ids  = (const int*)d_in[2];
  const int*   m2e        = (const int*)d_in[3];
  const int*   mpos       = (const int*)d_in[4];
  const float* x_glob     = (const float*)d_in[5];
  const float* cls_mod    = (const float*)d_in[6];
  const float* empty_emb  = (const float*)d_in[7];
  const float* cls_task   = (const float*)d_in[8];
  const float* pos_emb    = (const float*)d_in[9];
  const float* mod_attn_w = (const float*)d_in[10];
  const float* mod_attn_b = (const float*)d_in[11];
  const float* mod_rel    = (const float*)d_in[12];
  const float* mod_ln_s   = (const float*)d_in[13];
  const float* mod_ln_b   = (const float*)d_in[14];
  const float* mod_ffn_w1 = (const float*)d_in[15];
  const float* mod_ffn_b1 = (const float*)d_in[16];
  const float* mod_ffn_w2 = (const float*)d_in[17];
  const float* mod_ffn_b2 = (const float*)d_in[18];
  const float* glob_w1    = (const float*)d_in[19];
  const float* glob_b1    = (const float*)d_in[20];
  const float* glob_w2    = (const float*)d_in[21];
  const float* glob_b2    = (const float*)d_in[22];
  const float* evt_attn_w = (const float*)d_in[23];
  const float* evt_attn_b = (const float*)d_in[24];
  const float* evt_ln_s   = (const float*)d_in[25];
  const float* evt_ln_b   = (const float*)d_in[26];
  const float* evt_ffn_w1 = (const float*)d_in[27];
  const float* evt_ffn_b1 = (const float*)d_in[28];
  const float* evt_ffn_w2 = (const float*)d_in[29];
  const float* evt_ffn_b2 = (const float*)d_in[30];
  const float* head_w     = (const float*)d_in[31];
  const float* head_b     = (const float*)d_in[32];
  float* out = (float*)d_out;

  const int N = in_sizes[0] / 256;   // 53346
  const int M = in_sizes[3];         // 960
  const int B = in_sizes[5] / 16;    // 64
  const long CROWS   = (long)M + N;                       // 54306 compact rows
  const long CROWS_P = (((CROWS + 127) >> 7) << 7) + 128; // pad + overrun guard
  const long TE  = (long)B * NTOKE;  // 1472
  const long TEP = 1536;

  char* ws = (char*)d_ws;
  u16* modWT   = (u16*)ws;
  u16* evtWT   = modWT + 8L*65536;
  u16* modF1T  = evtWT + 12L*65536;
  u16* modF2T  = modF1T + 2L*262144;
  u16* evtF1T  = modF2T + 2L*262144;
  u16* evtF2T  = evtF1T + 3L*524288;
  u16* globW2T = evtF2T + 3L*524288;
  size_t off = 11468800;
  int* counts = (int*)(ws + off); off += 16*1024;
  int* starts = (int*)(ws + off); off += 16*1024;
  float* scc  = (float*)(ws + off); off += ((size_t)CROWS_P*12 + 255) & ~(size_t)255;
  u16* seqc   = (u16*)(ws + off); off += (size_t)CROWS_P * D_MOD * 2;
  off = (off + 255) & ~(size_t)255;
  const size_t OFF_BIG = off;
  u16* qkv   = (u16*)(ws + OFF_BIG);                           // CROWS_P x 768
  u16* attno = (u16*)(ws + OFF_BIG + (size_t)CROWS_P*768*2);   // CROWS_P x 256
  u16* ffh   = (u16*)(ws + OFF_BIG);                           // CROWS_P x 1024 (reuses both)
  u16* se    = (u16*)(ws + OFF_BIG);                           // event stage reuses BIG
  u16* qkvE  = (u16*)(ws + OFF_BIG + 1*1024*1024);
  u16* attnoE= (u16*)(ws + OFF_BIG + 4*1024*1024);
  u16* ffhE  = (u16*)(ws + OFF_BIG + 5*1024*1024);
  u16* globh = (u16*)(ws + OFF_BIG + 12*1024*1024);
  u16* globo = (u16*)(ws + OFF_BIG + 13*1024*1024);

  prep_t<<<dim3(8, 8, 8),   256, 0, stream>>>(mod_attn_w, modWT,   256, 256,  65536L, 65536L);
  prep_t<<<dim3(8, 8, 12),  256, 0, stream>>>(evt_attn_w, evtWT,   256, 256,  65536L, 65536L);
  prep_t<<<dim3(8, 32, 2),  256, 0, stream>>>(mod_ffn_w1, modF1T,  256, 1024, 262144L, 262144L);
  prep_t<<<dim3(32, 8, 2),  256, 0, stream>>>(mod_ffn_w2, modF2T,  1024, 256, 262144L, 262144L);
  prep_t<<<dim3(8, 64, 3),  256, 0, stream>>>(evt_ffn_w1, evtF1T,  256, 2048, 524288L, 524288L);
  prep_t<<<dim3(64, 8, 3),  256, 0, stream>>>(evt_ffn_w2, evtF2T,  2048, 256, 524288L, 524288L);
  prep_t<<<dim3(8, 8, 1),   256, 0, stream>>>(glob_w2,    globW2T, 256, 256,  65536L, 65536L);

  hipMemsetAsync(counts, 0, (size_t)M*4, stream);
  hipMemsetAsync(scc, 0, (size_t)CROWS_P*12, stream);
  hipMemsetAsync(seqc + CROWS*D_MOD, 0, (size_t)(CROWS_P - CROWS)*D_MOD*2, stream);
  count_k<<<(N + 255)/256, 256, 0, stream>>>(batch_ids, counts, N);
  scan_k<<<1, 1024, 0, stream>>>(counts, starts, M);
  cls_fill<<<M, 64, 0, stream>>>(seqc, cls_mod, starts);
  scatter_k<<<N, 64, 0, stream>>>(feats, coords, batch_ids, seqc, scc);

  const int RB = (int)(CROWS_P / 128);
  for (int l = 0; l < 2; l++){
    gemm128<0><<<dim3(6, RB), 256, 0, stream>>>(seqc, modWT + (long)l*4*65536,
        mod_attn_b + l*1024, nullptr, qkv, 256, 768);
    mod_attn_t<3><<<dim3(M, NHEAD), 256, 0, stream>>>(qkv, scc, mod_rel + l*24, counts, starts, attno, M, 0, 48);
    mod_attn_t<5><<<dim3(M, NHEAD), 256, 0, stream>>>(qkv, scc, mod_rel + l*24, counts, starts, attno, M, 48, 80);
    mod_attn_t<7><<<dim3(M, NHEAD), 256, 0, stream>>>(qkv, scc, mod_rel + l*24, counts, starts, attno, M, 80, 112);
    gemm128<3><<<dim3(2, RB), 256, 0, stream>>>(attno, modWT + ((long)l*4+3)*65536,
        mod_attn_b + l*1024 + 768, seqc, seqc, 256, 256);
    ln_k<<<(int)((CROWS + 3)/4), 256, 0, stream>>>(seqc, mod_ln_s + (l*2)*256, mod_ln_b + (l*2)*256, CROWS);
    gemm128<1><<<dim3(8, RB), 256, 0, stream>>>(seqc, modF1T + (long)l*262144,
        mod_ffn_b1 + l*1024, nullptr, ffh, 256, 1024);
    gemm128<3><<<dim3(2, RB), 256, 0, stream>>>(ffh, modF2T + (long)l*262144,
        mod_ffn_b2 + l*256, seqc, seqc, 1024, 256);
    ln_k<<<(int)((CROWS + 3)/4), 256, 0, stream>>>(seqc, mod_ln_s + (l*2+1)*256, mod_ln_b + (l*2+1)*256, CROWS);
  }

  hipMemsetAsync(globh, 0, 128*256*2, stream);
  hipMemsetAsync((void*)se, 0, (size_t)TEP*D_MOD*2, stream);
  glob1_k<<<B, 256, 0, stream>>>(x_glob, glob_w1, glob_b1, globh);
  gemm128<0><<<dim3(2, 1), 256, 0, stream>>>(globh, globW2T, glob_b2, nullptr, globo, 256, 256);
  fill_se<<<(int)TE, 64, 0, stream>>>(se, cls_task, globo, pos_emb, empty_emb);
  scatter_mod<<<M, 64, 0, stream>>>(se, seqc, m2e, mpos, starts, pos_emb);

  const int RE = (int)(TEP / 128);
  for (int l = 0; l < 3; l++){
    gemm128<0><<<dim3(6, RE), 256, 0, stream>>>(se, evtWT + (long)l*4*65536,
        evt_attn_b + l*1024, nullptr, qkvE, 256, 768);
    evt_attn<<<dim3(B, NHEAD), 64, 0, stream>>>(qkvE, attnoE);
    gemm128<3><<<dim3(2, RE), 256, 0, stream>>>(attnoE, evtWT + ((long)l*4+3)*65536,
        evt_attn_b + l*1024 + 768, se, se, 256, 256);
    ln_k<<<(int)((TE + 3)/4), 256, 0, stream>>>(se, evt_ln_s + (l*2)*256, evt_ln_b + (l*2)*256, TE);
    gemm128<2><<<dim3(16, RE), 256, 0, stream>>>(se, evtF1T + (long)l*524288,
        evt_ffn_b1 + l*2048, nullptr, ffhE, 256, 2048);
    gemm128<3><<<dim3(2, RE), 256, 0, stream>>>(ffhE, evtF2T + (long)l*524288,
        evt_ffn_b2 + l*256, se, se, 2048, 256);
    ln_k<<<(int)((TE + 3)/4), 256, 0, stream>>>(se, evt_ln_s + (l*2+1)*256, evt_ln_b + (l*2+1)*256, TE);
  }

  heads_k<<<B, 64, 0, stream>>>(se, head_w, head_b, out);
}